// Round 2
// baseline (325.672 us; speedup 1.0000x reference)
//
#include <hip/hip_runtime.h>
#include <math.h>

#define SMOOTH_F 1e-5f
#define ALPHA_F 0.25f

constexpr int Bn = 8;
constexpr int NCn = 1000;
constexpr int Cn = 19;
constexpr int HWn = 512 * 512;      // 262144
constexpr int Dn = 768;
constexpr int BC = Bn * Cn;         // 152

constexpr int TPB = 256;
constexpr int CHUNK = 512;                     // pixels per block
constexpr int CPB = HWn / CHUNK;               // 512 chunks per batch
constexpr int SEG_BLOCKS = Bn * CPB;           // 4096
constexpr int F4_PER_CLASS = CHUNK / 4;        // 128
constexpr int LDS_F4 = Cn * F4_PER_CLASS;      // 2432 float4 = 38 KB

// ws float-slot layout
constexpr int WS_INTER = 0;          // [0,152)   sum(pred * onehot) per (b,c)
constexpr int WS_PRED  = BC;         // [152,304) sum(pred) per (b,c)
constexpr int WS_CNT   = 2 * BC;     // [304,456) sum(onehot) per (b,c)
constexpr int WS_FOCAL = 3 * BC;     // 456 focal numerator sum
constexpr int WS_CE    = 3 * BC + 1; // 457 (direct store, no zero needed)
constexpr int WS_MB    = 3 * BC + 2; // 458 (direct store)
constexpr int WS_ZERO_N = WS_FOCAL + 1; // zero [0,457)

__device__ __forceinline__ float wave_sum(float v) {
#pragma unroll
  for (int off = 32; off > 0; off >>= 1) v += __shfl_down(v, off, 64);
  return v;
}
__device__ __forceinline__ float wave_max(float v) {
#pragma unroll
  for (int off = 32; off > 0; off >>= 1) v = fmaxf(v, __shfl_down(v, off, 64));
  return v;
}

// block 0: zero ws accumulators; block 1: cross-entropy; block 2: modal balance
__global__ __launch_bounds__(256) void k_pre(
    const float* __restrict__ logits, const int* __restrict__ label,
    const float* __restrict__ vf, const float* __restrict__ tf,
    const float* __restrict__ mmask, const int* __restrict__ epoch,
    float* __restrict__ ws) {
  __shared__ float sA[4];
  __shared__ float sBv[4];
  __shared__ float nv[Bn];
  __shared__ float nt[Bn];
  __shared__ float s3[3][4];
  const int tid = threadIdx.x;
  const int wid = tid >> 6, lane = tid & 63;

  if (blockIdx.x == 0) {
    for (int t = tid; t < WS_ZERO_N; t += TPB) ws[t] = 0.0f;
  } else if (blockIdx.x == 1) {
    // ---- cross entropy over logits[8,1000] ----
    float acc = 0.0f;
    for (int b = 0; b < Bn; ++b) {
      const float* row = logits + b * NCn;
      float lm = -INFINITY;
      for (int j = tid; j < NCn; j += TPB) lm = fmaxf(lm, row[j]);
      lm = wave_max(lm);
      if (lane == 0) sA[wid] = lm;
      __syncthreads();
      float bm = fmaxf(fmaxf(sA[0], sA[1]), fmaxf(sA[2], sA[3]));
      __syncthreads();
      float ls = 0.0f;
      for (int j = tid; j < NCn; j += TPB) ls += expf(row[j] - bm);
      ls = wave_sum(ls);
      if (lane == 0) sA[wid] = ls;
      __syncthreads();
      if (tid == 0) {
        float lse = bm + logf(sA[0] + sA[1] + sA[2] + sA[3]);
        acc += row[label[b]] - lse;
      }
      __syncthreads();
    }
    if (tid == 0) ws[WS_CE] = -(acc / (float)Bn);
  } else {
    // ---- modal balance ----
    for (int b = 0; b < Bn; ++b) {
      float sv = 0.0f, st = 0.0f;
      for (int j = tid; j < Dn; j += TPB) {
        float a = vf[b * Dn + j];
        float c = tf[b * Dn + j];
        sv += a * a;
        st += c * c;
      }
      sv = wave_sum(sv);
      st = wave_sum(st);
      if (lane == 0) { sA[wid] = sv; sBv[wid] = st; }
      __syncthreads();
      if (tid == 0) {
        nv[b] = sqrtf(sA[0] + sA[1] + sA[2] + sA[3]);
        nt[b] = sqrtf(sBv[0] + sBv[1] + sBv[2] + sBv[3]);
      }
      __syncthreads();
    }
    float colv = 0.0f, colt = 0.0f, cross = 0.0f;
    for (int j = tid; j < Dn; j += TPB) {
      float sv = 0.0f, ssv = 0.0f, stt = 0.0f, sst = 0.0f, cr = 0.0f;
      for (int b = 0; b < Bn; ++b) {
        float vn = vf[b * Dn + j] / nv[b];
        float tn = tf[b * Dn + j] / nt[b];
        sv += vn; ssv += vn * vn;
        stt += tn; sst += tn * tn;
        cr += vn * tn;
      }
      colv += ssv - sv * sv * 0.125f;
      colt += sst - stt * stt * 0.125f;
      cross += cr;
    }
    colv = wave_sum(colv);
    colt = wave_sum(colt);
    cross = wave_sum(cross);
    if (lane == 0) { s3[0][wid] = colv; s3[1][wid] = colt; s3[2][wid] = cross; }
    __syncthreads();
    if (tid == 0) {
      float cv = s3[0][0] + s3[0][1] + s3[0][2] + s3[0][3];
      float ct = s3[1][0] + s3[1][1] + s3[1][2] + s3[1][3];
      float cr = s3[2][0] + s3[2][1] + s3[2][2] + s3[2][3];
      float v_cons = cv / (float)(Bn * Dn);
      float t_cons = ct / (float)(Bn * Dn);
      float crossv = 1.0f - cr * 0.125f;
      float beta = 0.5f * powf(0.99f, (float)epoch[0]);
      float mm0 = 0.0f, mm1 = 0.0f;
      for (int b = 0; b < Bn; ++b) { mm0 += mmask[b * 2]; mm1 += mmask[b * 2 + 1]; }
      mm0 *= 0.125f; mm1 *= 0.125f;
      ws[WS_MB] = (1.0f - beta) * v_cons * mm0 + beta * t_cons * mm1 + crossv;
    }
  }
}

// fused dice-sums + focal over seg_mask [8,19,512,512], seg_gt [8,512,512]
// Class-major LDS staging: each block streams its 19 class segments as
// contiguous bursts (kills the 1 MiB-stride L2-set-alias / DRAM-stream blowup),
// then computes the 19-class softmax column-wise from LDS.
__global__ __launch_bounds__(TPB) void k_seg(
    const float* __restrict__ pred, const int* __restrict__ gt,
    float* __restrict__ ws) {
  __shared__ float lds[Cn * CHUNK];      // 38 KB
  __shared__ float s_inter[Cn];
  __shared__ float s_count[Cn];
  __shared__ float s_pred[Cn];
  __shared__ float s_red[4];

  const int tid = threadIdx.x;
  const int wid = tid >> 6, lane = tid & 63;
  const int b = blockIdx.x / CPB;
  const int chunk = blockIdx.x % CPB;

  if (tid < Cn) { s_inter[tid] = 0.0f; s_count[tid] = 0.0f; s_pred[tid] = 0.0f; }

  // ---- staging: linear index over 19 x 128 float4; consecutive i ->
  // consecutive memory within a class plane => long contiguous bursts ----
  const float4* pred4 = (const float4*)pred;
  float4* lds4 = (float4*)lds;
  const size_t pbase = (size_t)b * Cn * (HWn / 4) + (size_t)chunk * F4_PER_CLASS;
  for (int i = tid; i < LDS_F4; i += TPB) {
    const int c = i >> 7;        // / F4_PER_CLASS (128)
    const int off = i & 127;
    lds4[i] = pred4[pbase + (size_t)c * (HWn / 4) + off];
  }
  const int2 t2 = ((const int2*)(gt + (size_t)b * HWn))[chunk * (CHUNK / 2) + tid];
  __syncthreads();

  // ---- compute: 2 pixels per thread, all 19 classes from LDS ----
  const float2* lds2 = (const float2*)lds;
  float2 xs[Cn];
#pragma unroll
  for (int c = 0; c < Cn; ++c) xs[c] = lds2[c * (CHUNK / 2) + tid];

  float m0 = xs[0].x, m1 = xs[0].y;
#pragma unroll
  for (int c = 1; c < Cn; ++c) {
    m0 = fmaxf(m0, xs[c].x);
    m1 = fmaxf(m1, xs[c].y);
  }
  float se0 = 0.0f, se1 = 0.0f, xt0 = 0.0f, xt1 = 0.0f;
  float psum[Cn];
#pragma unroll
  for (int c = 0; c < Cn; ++c) {
    se0 += expf(xs[c].x - m0);
    se1 += expf(xs[c].y - m1);
    if (t2.x == c) xt0 = xs[c].x;
    if (t2.y == c) xt1 = xs[c].y;
    psum[c] = xs[c].x + xs[c].y;
  }
  const float lse0 = m0 + logf(se0);
  const float lse1 = m1 + logf(se1);

  float focal;
  {
    float lpt, p, om;
    lpt = xt0 - lse0; p = expf(lpt); om = 1.0f - p; focal = om * om * (-lpt);
    lpt = xt1 - lse1; p = expf(lpt); om = 1.0f - p; focal += om * om * (-lpt);
  }
  focal *= ALPHA_F;

  atomicAdd(&s_inter[t2.x], xt0);
  atomicAdd(&s_inter[t2.y], xt1);
  atomicAdd(&s_count[t2.x], 1.0f);
  atomicAdd(&s_count[t2.y], 1.0f);

  const float fw = wave_sum(focal);
  if (lane == 0) s_red[wid] = fw;
#pragma unroll
  for (int c = 0; c < Cn; ++c) {
    const float v = wave_sum(psum[c]);
    if (lane == 0) atomicAdd(&s_pred[c], v);
  }
  __syncthreads();

  if (tid < Cn) {
    atomicAdd(&ws[WS_INTER + b * Cn + tid], s_inter[tid]);
    atomicAdd(&ws[WS_PRED + b * Cn + tid], s_pred[tid]);
    atomicAdd(&ws[WS_CNT + b * Cn + tid], s_count[tid]);
  }
  if (tid == 0)
    atomicAdd(&ws[WS_FOCAL], s_red[0] + s_red[1] + s_red[2] + s_red[3]);
}

__global__ __launch_bounds__(256) void k_final(
    const float* __restrict__ ws, float* __restrict__ out) {
  __shared__ float sA[4];
  const int tid = threadIdx.x;
  const int wid = tid >> 6, lane = tid & 63;
  float v = 0.0f;
  if (tid < BC) {
    const float inter = ws[WS_INTER + tid];
    const float ps = ws[WS_PRED + tid];
    const float cnt = ws[WS_CNT + tid];
    const float dice = (2.0f * inter + SMOOTH_F) / (ps + cnt + SMOOTH_F);
    v = 1.0f - dice;
  }
  v = wave_sum(v);
  if (lane == 0) sA[wid] = v;
  __syncthreads();
  if (tid == 0) {
    const float dice_mean = (sA[0] + sA[1] + sA[2] + sA[3]) / (float)BC;
    const float focal_mean = ws[WS_FOCAL] / (float)(Bn * HWn);
    const float seg = dice_mean + focal_mean;
    out[0] = ws[WS_CE] + 0.3f * ws[WS_MB] + 0.5f * seg;
  }
}

extern "C" void kernel_launch(void* const* d_in, const int* in_sizes, int n_in,
                              void* d_out, int out_size, void* d_ws, size_t ws_size,
                              hipStream_t stream) {
  const float* logits = (const float*)d_in[0];
  const int* label    = (const int*)d_in[1];
  const float* vf     = (const float*)d_in[2];
  const float* tf     = (const float*)d_in[3];
  const float* mmask  = (const float*)d_in[4];
  const float* seg    = (const float*)d_in[5];
  const int* gt       = (const int*)d_in[6];
  const int* epoch    = (const int*)d_in[7];
  float* out = (float*)d_out;
  float* ws = (float*)d_ws;

  hipLaunchKernelGGL(k_pre, dim3(3), dim3(256), 0, stream,
                     logits, label, vf, tf, mmask, epoch, ws);
  hipLaunchKernelGGL(k_seg, dim3(SEG_BLOCKS), dim3(TPB), 0, stream, seg, gt, ws);
  hipLaunchKernelGGL(k_final, dim3(1), dim3(256), 0, stream, ws, out);
}

// Round 3
// 290.570 us; speedup vs baseline: 1.1208x; 1.1208x over previous
//
#include <hip/hip_runtime.h>
#include <math.h>

#define SMOOTH_F 1e-5f
#define ALPHA_F 0.25f

constexpr int Bn = 8;
constexpr int NCn = 1000;
constexpr int Cn = 19;
constexpr int HWn = 512 * 512;      // 262144
constexpr int Dn = 768;
constexpr int BC = Bn * Cn;         // 152

constexpr int TPB = 256;
constexpr int CHUNK = 512;                     // pixels per staged chunk
constexpr int CPB = HWn / CHUNK;               // 512 chunks per batch
constexpr int ITERS = 4;                       // chunks per block (consecutive)
constexpr int BLKS_PER_B = CPB / ITERS;        // 128
constexpr int SEG_BLOCKS = Bn * BLKS_PER_B;    // 1024 (persistent, 4/CU)
constexpr int F4_PER_CLASS = CHUNK / 4;        // 128
constexpr int LDS_F4 = Cn * F4_PER_CLASS;      // 2432 float4 = 38 KB

// ws float-slot layout: per-block partials, no atomics anywhere.
// partial[blk][0..19)  = inter per class
// partial[blk][19..38) = pred-sum per class
// partial[blk][38..57) = onehot count per class
// partial[blk][57]     = focal partial
constexpr int PART_STRIDE = 58;
constexpr int WS_CE = SEG_BLOCKS * PART_STRIDE;     // 59392
constexpr int WS_MB = WS_CE + 1;                    // 59393

__device__ __forceinline__ float wave_sum(float v) {
#pragma unroll
  for (int off = 32; off > 0; off >>= 1) v += __shfl_down(v, off, 64);
  return v;
}
__device__ __forceinline__ float wave_max(float v) {
#pragma unroll
  for (int off = 32; off > 0; off >>= 1) v = fmaxf(v, __shfl_down(v, off, 64));
  return v;
}

// block 0: cross-entropy; block 1: modal balance
__global__ __launch_bounds__(256) void k_pre(
    const float* __restrict__ logits, const int* __restrict__ label,
    const float* __restrict__ vf, const float* __restrict__ tf,
    const float* __restrict__ mmask, const int* __restrict__ epoch,
    float* __restrict__ ws) {
  __shared__ float sA[4];
  __shared__ float sBv[4];
  __shared__ float nv[Bn];
  __shared__ float nt[Bn];
  __shared__ float s3[3][4];
  const int tid = threadIdx.x;
  const int wid = tid >> 6, lane = tid & 63;

  if (blockIdx.x == 0) {
    // ---- cross entropy over logits[8,1000] ----
    float acc = 0.0f;
    for (int b = 0; b < Bn; ++b) {
      const float* row = logits + b * NCn;
      float lm = -INFINITY;
      for (int j = tid; j < NCn; j += TPB) lm = fmaxf(lm, row[j]);
      lm = wave_max(lm);
      if (lane == 0) sA[wid] = lm;
      __syncthreads();
      float bm = fmaxf(fmaxf(sA[0], sA[1]), fmaxf(sA[2], sA[3]));
      __syncthreads();
      float ls = 0.0f;
      for (int j = tid; j < NCn; j += TPB) ls += expf(row[j] - bm);
      ls = wave_sum(ls);
      if (lane == 0) sA[wid] = ls;
      __syncthreads();
      if (tid == 0) {
        float lse = bm + logf(sA[0] + sA[1] + sA[2] + sA[3]);
        acc += row[label[b]] - lse;
      }
      __syncthreads();
    }
    if (tid == 0) ws[WS_CE] = -(acc / (float)Bn);
  } else {
    // ---- modal balance ----
    for (int b = 0; b < Bn; ++b) {
      float sv = 0.0f, st = 0.0f;
      for (int j = tid; j < Dn; j += TPB) {
        float a = vf[b * Dn + j];
        float c = tf[b * Dn + j];
        sv += a * a;
        st += c * c;
      }
      sv = wave_sum(sv);
      st = wave_sum(st);
      if (lane == 0) { sA[wid] = sv; sBv[wid] = st; }
      __syncthreads();
      if (tid == 0) {
        nv[b] = sqrtf(sA[0] + sA[1] + sA[2] + sA[3]);
        nt[b] = sqrtf(sBv[0] + sBv[1] + sBv[2] + sBv[3]);
      }
      __syncthreads();
    }
    float colv = 0.0f, colt = 0.0f, cross = 0.0f;
    for (int j = tid; j < Dn; j += TPB) {
      float sv = 0.0f, ssv = 0.0f, stt = 0.0f, sst = 0.0f, cr = 0.0f;
      for (int b = 0; b < Bn; ++b) {
        float vn = vf[b * Dn + j] / nv[b];
        float tn = tf[b * Dn + j] / nt[b];
        sv += vn; ssv += vn * vn;
        stt += tn; sst += tn * tn;
        cr += vn * tn;
      }
      colv += ssv - sv * sv * 0.125f;
      colt += sst - stt * stt * 0.125f;
      cross += cr;
    }
    colv = wave_sum(colv);
    colt = wave_sum(colt);
    cross = wave_sum(cross);
    if (lane == 0) { s3[0][wid] = colv; s3[1][wid] = colt; s3[2][wid] = cross; }
    __syncthreads();
    if (tid == 0) {
      float cv = s3[0][0] + s3[0][1] + s3[0][2] + s3[0][3];
      float ct = s3[1][0] + s3[1][1] + s3[1][2] + s3[1][3];
      float cr = s3[2][0] + s3[2][1] + s3[2][2] + s3[2][3];
      float v_cons = cv / (float)(Bn * Dn);
      float t_cons = ct / (float)(Bn * Dn);
      float crossv = 1.0f - cr * 0.125f;
      float beta = 0.5f * powf(0.99f, (float)epoch[0]);
      float mm0 = 0.0f, mm1 = 0.0f;
      for (int b = 0; b < Bn; ++b) { mm0 += mmask[b * 2]; mm1 += mmask[b * 2 + 1]; }
      mm0 *= 0.125f; mm1 *= 0.125f;
      ws[WS_MB] = (1.0f - beta) * v_cons * mm0 + beta * t_cons * mm1 + crossv;
    }
  }
}

// fused dice-sums + focal over seg_mask [8,19,512,512], seg_gt [8,512,512].
// Persistent blocks: each block stages 4 consecutive 512-pixel chunks
// (class-major LDS staging = contiguous 8 KB bursts per class per block),
// accumulates psum/focal in registers and inter/count in LDS across chunks,
// pays the wave-reduction tail ONCE, writes 58 partials (no atomics).
__global__ __launch_bounds__(TPB) void k_seg(
    const float* __restrict__ pred, const int* __restrict__ gt,
    float* __restrict__ ws) {
  __shared__ float lds[Cn * CHUNK];      // 38 KB
  __shared__ float s_inter[Cn];
  __shared__ float s_count[Cn];
  __shared__ float s_pred[Cn];
  __shared__ float s_red[4];

  const int tid = threadIdx.x;
  const int wid = tid >> 6, lane = tid & 63;
  const int blk = blockIdx.x;
  const int b = blk >> 7;          // / BLKS_PER_B (128)
  const int local = blk & 127;

  if (tid < Cn) { s_inter[tid] = 0.0f; s_count[tid] = 0.0f; s_pred[tid] = 0.0f; }

  const float4* pred4 = (const float4*)pred;
  float4* lds4 = (float4*)lds;
  const float2* lds2 = (const float2*)lds;
  const int2* gt2 = (const int2*)(gt + (size_t)b * HWn);

  float psum[Cn];
#pragma unroll
  for (int c = 0; c < Cn; ++c) psum[c] = 0.0f;
  float focal = 0.0f;

#pragma unroll 1
  for (int it = 0; it < ITERS; ++it) {
    const int chunk = local * ITERS + it;
    __syncthreads();   // previous compute done (and init visible) before overwrite
    const size_t pbase = (size_t)b * Cn * (HWn / 4) + (size_t)chunk * F4_PER_CLASS;
#pragma unroll
    for (int k = 0; k < 10; ++k) {
      const int i = k * TPB + tid;
      if (i < LDS_F4) {
        const int c = i >> 7;        // / F4_PER_CLASS
        const int off = i & 127;
        lds4[i] = pred4[pbase + (size_t)c * (HWn / 4) + off];
      }
    }
    const int2 t2 = gt2[chunk * (CHUNK / 2) + tid];
    __syncthreads();

    float2 xs[Cn];
#pragma unroll
    for (int c = 0; c < Cn; ++c) xs[c] = lds2[c * (CHUNK / 2) + tid];

    float m0 = xs[0].x, m1 = xs[0].y;
#pragma unroll
    for (int c = 1; c < Cn; ++c) {
      m0 = fmaxf(m0, xs[c].x);
      m1 = fmaxf(m1, xs[c].y);
    }
    float se0 = 0.0f, se1 = 0.0f, xt0 = 0.0f, xt1 = 0.0f;
#pragma unroll
    for (int c = 0; c < Cn; ++c) {
      se0 += expf(xs[c].x - m0);
      se1 += expf(xs[c].y - m1);
      if (t2.x == c) xt0 = xs[c].x;
      if (t2.y == c) xt1 = xs[c].y;
      psum[c] += xs[c].x + xs[c].y;
    }
    const float lse0 = m0 + logf(se0);
    const float lse1 = m1 + logf(se1);
    {
      float lpt, p, om;
      lpt = xt0 - lse0; p = expf(lpt); om = 1.0f - p; focal += om * om * (-lpt);
      lpt = xt1 - lse1; p = expf(lpt); om = 1.0f - p; focal += om * om * (-lpt);
    }
    atomicAdd(&s_inter[t2.x], xt0);
    atomicAdd(&s_inter[t2.y], xt1);
    atomicAdd(&s_count[t2.x], 1.0f);
    atomicAdd(&s_count[t2.y], 1.0f);
  }

  // ---- tail: once per block ----
  const float fw = wave_sum(focal * ALPHA_F);
  if (lane == 0) s_red[wid] = fw;
#pragma unroll
  for (int c = 0; c < Cn; ++c) {
    const float v = wave_sum(psum[c]);
    if (lane == 0) atomicAdd(&s_pred[c], v);   // LDS, 4 waves only
  }
  __syncthreads();

  float* part = ws + (size_t)blk * PART_STRIDE;
  if (tid < Cn) {
    part[tid] = s_inter[tid];
    part[Cn + tid] = s_pred[tid];
    part[2 * Cn + tid] = s_count[tid];
  }
  if (tid == 0)
    part[57] = s_red[0] + s_red[1] + s_red[2] + s_red[3];
}

// reduce 1024 x 58 partials -> final scalar
__global__ __launch_bounds__(1024) void k_final(
    const float* __restrict__ ws, float* __restrict__ out) {
  __shared__ float s_i[BC * 4];
  __shared__ float s_p[BC * 4];
  __shared__ float s_c[BC * 4];
  __shared__ float s_f[16];
  __shared__ float s_d[3];
  const int tid = threadIdx.x;
  const int wid = tid >> 6, lane = tid & 63;

  // focal: one partial per thread (1024 blocks)
  float f = ws[(size_t)tid * PART_STRIDE + 57];
  f = wave_sum(f);
  if (lane == 0) s_f[wid] = f;

  // dice sums: 152 (b,c) pairs x 4 groups of 32 blocks
  if (tid < BC * 4) {
    const int g = tid / BC;
    const int p = tid - g * BC;
    const int b = p / Cn;
    const int c = p - b * Cn;
    const int base = b * 128 + g * 32;
    float si = 0.0f, sp = 0.0f, sc = 0.0f;
#pragma unroll 4
    for (int k = 0; k < 32; ++k) {
      const float* part = ws + (size_t)(base + k) * PART_STRIDE;
      si += part[c];
      sp += part[Cn + c];
      sc += part[2 * Cn + c];
    }
    s_i[p * 4 + g] = si;
    s_p[p * 4 + g] = sp;
    s_c[p * 4 + g] = sc;
  }
  __syncthreads();

  float v = 0.0f;
  if (tid < BC) {
    const float inter = s_i[tid * 4] + s_i[tid * 4 + 1] + s_i[tid * 4 + 2] + s_i[tid * 4 + 3];
    const float ps = s_p[tid * 4] + s_p[tid * 4 + 1] + s_p[tid * 4 + 2] + s_p[tid * 4 + 3];
    const float cnt = s_c[tid * 4] + s_c[tid * 4 + 1] + s_c[tid * 4 + 2] + s_c[tid * 4 + 3];
    const float dice = (2.0f * inter + SMOOTH_F) / (ps + cnt + SMOOTH_F);
    v = 1.0f - dice;
  }
  v = wave_sum(v);
  if (lane == 0 && wid < 3) s_d[wid] = v;
  __syncthreads();

  if (tid == 0) {
    const float dice_mean = (s_d[0] + s_d[1] + s_d[2]) / (float)BC;
    float fs = 0.0f;
#pragma unroll
    for (int w = 0; w < 16; ++w) fs += s_f[w];
    const float focal_mean = fs / (float)(Bn * HWn);
    const float seg = dice_mean + focal_mean;
    out[0] = ws[WS_CE] + 0.3f * ws[WS_MB] + 0.5f * seg;
  }
}

extern "C" void kernel_launch(void* const* d_in, const int* in_sizes, int n_in,
                              void* d_out, int out_size, void* d_ws, size_t ws_size,
                              hipStream_t stream) {
  const float* logits = (const float*)d_in[0];
  const int* label    = (const int*)d_in[1];
  const float* vf     = (const float*)d_in[2];
  const float* tf     = (const float*)d_in[3];
  const float* mmask  = (const float*)d_in[4];
  const float* seg    = (const float*)d_in[5];
  const int* gt       = (const int*)d_in[6];
  const int* epoch    = (const int*)d_in[7];
  float* out = (float*)d_out;
  float* ws = (float*)d_ws;

  hipLaunchKernelGGL(k_pre, dim3(2), dim3(256), 0, stream,
                     logits, label, vf, tf, mmask, epoch, ws);
  hipLaunchKernelGGL(k_seg, dim3(SEG_BLOCKS), dim3(TPB), 0, stream, seg, gt, ws);
  hipLaunchKernelGGL(k_final, dim3(1), dim3(1024), 0, stream, ws, out);
}

// Round 4
// 274.428 us; speedup vs baseline: 1.1867x; 1.0588x over previous
//
#include <hip/hip_runtime.h>
#include <math.h>

#define SMOOTH_F 1e-5f
#define ALPHA_F 0.25f

constexpr int Bn = 8;
constexpr int NCn = 1000;
constexpr int Cn = 19;
constexpr int HWn = 512 * 512;
constexpr int Dn = 768;
constexpr int BC = Bn * Cn;

constexpr int TPB = 256;
constexpr int CHUNK = 256;                     // pixels per staged chunk (1 px/thread)
constexpr int ITERS = 4;                       // consecutive chunks per block
constexpr int PX_PER_BLK = CHUNK * ITERS;      // 1024
constexpr int BLKS_PER_B = HWn / PX_PER_BLK;   // 256
constexpr int SEG_BLOCKS = Bn * BLKS_PER_B;    // 2048
constexpr int F4_PER_CLASS = CHUNK / 4;        // 64
constexpr int LDS_F4 = Cn * F4_PER_CLASS;      // 1216 float4 = 19 KB

constexpr int PART_STRIDE = 58;
constexpr int WS_CE = SEG_BLOCKS * PART_STRIDE;
constexpr int WS_MB = WS_CE + 1;

__device__ __forceinline__ float wave_sum(float v) {
#pragma unroll
  for (int off = 32; off > 0; off >>= 1) v += __shfl_down(v, off, 64);
  return v;
}
__device__ __forceinline__ float wave_max(float v) {
#pragma unroll
  for (int off = 32; off > 0; off >>= 1) v = fmaxf(v, __shfl_down(v, off, 64));
  return v;
}

__global__ __launch_bounds__(TPB, 6) void k_seg(
    const float* __restrict__ pred, const int* __restrict__ gt,
    const float* __restrict__ logits, const int* __restrict__ label,
    const float* __restrict__ vf, const float* __restrict__ tf,
    const float* __restrict__ mmask, const int* __restrict__ epoch,
    float* __restrict__ ws) {
  __shared__ float lds[Cn * CHUNK];      // 19 KB
  __shared__ float s_inter[Cn];
  __shared__ float s_count[Cn];
  __shared__ float s_pred[Cn];
  __shared__ float s_red[4];
  __shared__ float sA[4];
  __shared__ float sBv[4];
  __shared__ float nv[Bn];
  __shared__ float nt[Bn];

  const int tid = threadIdx.x;
  const int wid = tid >> 6, lane = tid & 63;
  const int blk = blockIdx.x;

  if (blk >= SEG_BLOCKS) {
    if (blk == SEG_BLOCKS) {
      // ---- cross entropy over logits[8,1000] ----
      float acc = 0.0f;
      for (int b = 0; b < Bn; ++b) {
        const float* row = logits + b * NCn;
        float lm = -INFINITY;
        for (int j = tid; j < NCn; j += TPB) lm = fmaxf(lm, row[j]);
        lm = wave_max(lm);
        if (lane == 0) sA[wid] = lm;
        __syncthreads();
        float bm = fmaxf(fmaxf(sA[0], sA[1]), fmaxf(sA[2], sA[3]));
        __syncthreads();
        float ls = 0.0f;
        for (int j = tid; j < NCn; j += TPB) ls += expf(row[j] - bm);
        ls = wave_sum(ls);
        if (lane == 0) sA[wid] = ls;
        __syncthreads();
        if (tid == 0) {
          float lse = bm + logf(sA[0] + sA[1] + sA[2] + sA[3]);
          acc += row[label[b]] - lse;
        }
        __syncthreads();
      }
      if (tid == 0) ws[WS_CE] = -(acc / (float)Bn);
    } else {
      // ---- modal balance ----
      for (int b = 0; b < Bn; ++b) {
        float sv = 0.0f, st = 0.0f;
        for (int j = tid; j < Dn; j += TPB) {
          float a = vf[b * Dn + j];
          float c = tf[b * Dn + j];
          sv += a * a;
          st += c * c;
        }
        sv = wave_sum(sv);
        st = wave_sum(st);
        if (lane == 0) { sA[wid] = sv; sBv[wid] = st; }
        __syncthreads();
        if (tid == 0) {
          nv[b] = sqrtf(sA[0] + sA[1] + sA[2] + sA[3]);
          nt[b] = sqrtf(sBv[0] + sBv[1] + sBv[2] + sBv[3]);
        }
        __syncthreads();
      }
      float colv = 0.0f, colt = 0.0f, cross = 0.0f;
      for (int j = tid; j < Dn; j += TPB) {
        float sv = 0.0f, ssv = 0.0f, stt = 0.0f, sst = 0.0f, cr = 0.0f;
        for (int b = 0; b < Bn; ++b) {
          float vn = vf[b * Dn + j] / nv[b];
          float tn = tf[b * Dn + j] / nt[b];
          sv += vn; ssv += vn * vn;
          stt += tn; sst += tn * tn;
          cr += vn * tn;
        }
        colv += ssv - sv * sv * 0.125f;
        colt += sst - stt * stt * 0.125f;
        cross += cr;
      }
      colv = wave_sum(colv);
      colt = wave_sum(colt);
      cross = wave_sum(cross);
      if (lane == 0) { sA[wid] = colv; sBv[wid] = colt; s_red[wid] = cross; }
      __syncthreads();
      if (tid == 0) {
        float cv = sA[0] + sA[1] + sA[2] + sA[3];
        float ct = sBv[0] + sBv[1] + sBv[2] + sBv[3];
        float cr = s_red[0] + s_red[1] + s_red[2] + s_red[3];
        float v_cons = cv / (float)(Bn * Dn);
        float t_cons = ct / (float)(Bn * Dn);
        float crossv = 1.0f - cr * 0.125f;
        float beta = 0.5f * powf(0.99f, (float)epoch[0]);
        float mm0 = 0.0f, mm1 = 0.0f;
        for (int b = 0; b < Bn; ++b) { mm0 += mmask[b * 2]; mm1 += mmask[b * 2 + 1]; }
        mm0 *= 0.125f; mm1 *= 0.125f;
        ws[WS_MB] = (1.0f - beta) * v_cons * mm0 + beta * t_cons * mm1 + crossv;
      }
    }
    return;
  }

  // ================= segmentation path =================
  const int b = blk >> 8;            // / BLKS_PER_B
  const int local = blk & 255;

  if (tid < Cn) { s_inter[tid] = 0.0f; s_count[tid] = 0.0f; s_pred[tid] = 0.0f; }

  const float4* pred4 = (const float4*)pred;
  float4* lds4 = (float4*)lds;
  const int* gtb = gt + (size_t)b * HWn;

  float psum[Cn];
#pragma unroll
  for (int c = 0; c < Cn; ++c) psum[c] = 0.0f;
  float focal = 0.0f;

#pragma unroll 1
  for (int it = 0; it < ITERS; ++it) {
    const int chunk = local * ITERS + it;
    __syncthreads();   // prior compute (and init) done before LDS overwrite
    const size_t pbase = (size_t)b * Cn * (HWn / 4) + (size_t)chunk * F4_PER_CLASS;
#pragma unroll
    for (int k = 0; k < 5; ++k) {
      const int i = k * TPB + tid;
      if (i < LDS_F4) {
        const int c = i >> 6;
        const int off = i & 63;
        const float4* g = pred4 + pbase + (size_t)c * (HWn / 4) + off;
        __builtin_amdgcn_global_load_lds(
            (const __attribute__((address_space(1))) void*)g,
            (__attribute__((address_space(3))) void*)(lds4 + i), 16, 0, 0);
      }
    }
    const int t = gtb[chunk * CHUNK + tid];
    __syncthreads();   // barrier drain waits vmcnt(0) -> staged data visible

    float xs[Cn];
#pragma unroll
    for (int c = 0; c < Cn; ++c) xs[c] = lds[c * CHUNK + tid];

    float m = xs[0];
#pragma unroll
    for (int c = 1; c < Cn; ++c) m = fmaxf(m, xs[c]);
    float se = 0.0f, xt = 0.0f;
#pragma unroll
    for (int c = 0; c < Cn; ++c) {
      se += expf(xs[c] - m);
      if (t == c) xt = xs[c];
      psum[c] += xs[c];
    }
    const float lse = m + logf(se);
    const float lpt = xt - lse;
    const float p = expf(lpt);
    const float om = 1.0f - p;
    focal += om * om * (-lpt);

    atomicAdd(&s_inter[t], xt);
    atomicAdd(&s_count[t], 1.0f);
  }

  // ---- tail: once per block ----
  const float fw = wave_sum(focal * ALPHA_F);
  if (lane == 0) s_red[wid] = fw;
#pragma unroll
  for (int c = 0; c < Cn; ++c) {
    const float v = wave_sum(psum[c]);
    if (lane == 0) atomicAdd(&s_pred[c], v);   // LDS atomic, 4 waves
  }
  __syncthreads();

  float* part = ws + (size_t)blk * PART_STRIDE;
  if (tid < Cn) {
    part[tid] = s_inter[tid];
    part[Cn + tid] = s_pred[tid];
    part[2 * Cn + tid] = s_count[tid];
  }
  if (tid == 0)
    part[57] = s_red[0] + s_red[1] + s_red[2] + s_red[3];
}

// reduce 2048 x 58 partials -> final scalar
__global__ __launch_bounds__(1024) void k_final(
    const float* __restrict__ ws, float* __restrict__ out) {
  __shared__ float s_i[BC * 4];
  __shared__ float s_p[BC * 4];
  __shared__ float s_c[BC * 4];
  __shared__ float s_f[16];
  __shared__ float s_d[3];
  const int tid = threadIdx.x;
  const int wid = tid >> 6, lane = tid & 63;

  float f = ws[(size_t)(2 * tid) * PART_STRIDE + 57] +
            ws[(size_t)(2 * tid + 1) * PART_STRIDE + 57];
  f = wave_sum(f);
  if (lane == 0) s_f[wid] = f;

  if (tid < BC * 4) {
    const int g = tid / BC;
    const int p = tid - g * BC;
    const int b = p / Cn;
    const int c = p - b * Cn;
    const int base = b * 256 + g * 64;
    float si = 0.0f, sp = 0.0f, sc = 0.0f;
#pragma unroll 4
    for (int k = 0; k < 64; ++k) {
      const float* part = ws + (size_t)(base + k) * PART_STRIDE;
      si += part[c];
      sp += part[Cn + c];
      sc += part[2 * Cn + c];
    }
    s_i[p * 4 + g] = si;
    s_p[p * 4 + g] = sp;
    s_c[p * 4 + g] = sc;
  }
  __syncthreads();

  float v = 0.0f;
  if (tid < BC) {
    const float inter = s_i[tid * 4] + s_i[tid * 4 + 1] + s_i[tid * 4 + 2] + s_i[tid * 4 + 3];
    const float ps = s_p[tid * 4] + s_p[tid * 4 + 1] + s_p[tid * 4 + 2] + s_p[tid * 4 + 3];
    const float cnt = s_c[tid * 4] + s_c[tid * 4 + 1] + s_c[tid * 4 + 2] + s_c[tid * 4 + 3];
    const float dice = (2.0f * inter + SMOOTH_F) / (ps + cnt + SMOOTH_F);
    v = 1.0f - dice;
  }
  v = wave_sum(v);
  if (lane == 0 && wid < 3) s_d[wid] = v;
  __syncthreads();

  if (tid == 0) {
    const float dice_mean = (s_d[0] + s_d[1] + s_d[2]) / (float)BC;
    float fs = 0.0f;
#pragma unroll
    for (int w = 0; w < 16; ++w) fs += s_f[w];
    const float focal_mean = fs / (float)(Bn * HWn);
    const float seg = dice_mean + focal_mean;
    out[0] = ws[WS_CE] + 0.3f * ws[WS_MB] + 0.5f * seg;
  }
}

extern "C" void kernel_launch(void* const* d_in, const int* in_sizes, int n_in,
                              void* d_out, int out_size, void* d_ws, size_t ws_size,
                              hipStream_t stream) {
  const float* logits = (const float*)d_in[0];
  const int* label    = (const int*)d_in[1];
  const float* vf     = (const float*)d_in[2];
  const float* tf     = (const float*)d_in[3];
  const float* mmask  = (const float*)d_in[4];
  const float* seg    = (const float*)d_in[5];
  const int* gt       = (const int*)d_in[6];
  const int* epoch    = (const int*)d_in[7];
  float* out = (float*)d_out;
  float* ws = (float*)d_ws;

  hipLaunchKernelGGL(k_seg, dim3(SEG_BLOCKS + 2), dim3(TPB), 0, stream,
                     seg, gt, logits, label, vf, tf, mmask, epoch, ws);
  hipLaunchKernelGGL(k_final, dim3(1), dim3(1024), 0, stream, ws, out);
}